// Round 1
// baseline (1667.450 us; speedup 1.0000x reference)
//
#include <hip/hip_runtime.h>
#include <math.h>

// SSD decode + per-class greedy NMS + per-image top-k for MI355X (gfx950).
//
// Exactness strategy: the reference makes hard comparisons (score > 0.5,
// IoU > 0.45) on fp32 values. Any ulp deviation in decode/IoU can flip a
// selection and change the output by hundreds. So:
//  - fp contract OFF (no FMA fusion; every op individually rounded fp32,
//    identical to XLA-CPU/numpy evaluation of the same expression tree)
//  - exp computed in double, rounded to fp32 (correctly-rounded expf)
//  - f32 division left as IEEE (default HIP codegen: div_scale/div_fmas)
//  - argmax tie-break = lowest index (matches jnp.argmax), top_k tie-break
//    = lowest flat index (matches lax.top_k), both via packed u64 keys.

#pragma clang fp contract(off)

#define NANCH 8732
#define NB 64
#define NCLS 20            // foreground classes (class ids 1..20)
#define NMSMAX 100
#define TOPK 200
#define PRED_STRIDE 33     // 21 conf + 4 loc + 4 anchor + 4 var
#define NTHR 512
#define NE 18              // ceil(8732/512)
#define NEGF -1e30f

__device__ __forceinline__ unsigned flipf(float f) {
  unsigned u = __float_as_uint(f);
  return u ^ ((u >> 31) ? 0xFFFFFFFFu : 0x80000000u);
}

// ---------------------------------------------------------------- decode ---
__global__ void decode_kernel(const float* __restrict__ pred,
                              float* __restrict__ boxes,
                              float* __restrict__ scores_t) {
#pragma clang fp contract(off)
  long long idx = (long long)blockIdx.x * blockDim.x + threadIdx.x;
  if (idx >= (long long)NB * NANCH) return;
  int b = (int)(idx / NANCH);
  int n = (int)(idx % NANCH);
  const float* row = pred + idx * PRED_STRIDE;

  float l0 = row[21], l1 = row[22], l2 = row[23], l3 = row[24];
  float ax = row[25], ay = row[26], aw = row[27], ah = row[28];
  float v0 = row[29], v1 = row[30], v2 = row[31], v3 = row[32];

  float cx = (l0 * v0) * aw + ax;          // ((l*v)*a)+a, left-assoc like ref
  float cy = (l1 * v1) * ah + ay;
  float t2 = l2 * v2;
  float t3 = l3 * v3;
  float e2 = (float)exp((double)t2);       // correctly-rounded fp32 exp
  float e3 = (float)exp((double)t3);
  float w = e2 * aw;
  float h = e3 * ah;
  float hw = 0.5f * w, hh = 0.5f * h;      // exact (power-of-2 scale)
  float xmin = (cx - hw) * 300.0f;
  float ymin = (cy - hh) * 300.0f;
  float xmax = (cx + hw) * 300.0f;
  float ymax = (cy + hh) * 300.0f;

  *(float4*)(boxes + idx * 4) = make_float4(xmin, ymin, xmax, ymax);

  if (scores_t) {
#pragma unroll
    for (int c = 0; c < NCLS; ++c) {
      scores_t[((long long)b * NCLS + c) * NANCH + n] = row[1 + c];
    }
  }
}

// ------------------------------------------------------------------- NMS ---
// One 512-thread block per (image, class). Element i owned by thread i%512,
// slot k = i/512. Scores (orderable-u32) live in LDS, boxes in registers.
__global__ __launch_bounds__(NTHR) void nms_kernel(
    const float* __restrict__ boxes,
    const float* __restrict__ scores_t,   // may be null -> strided fallback
    const float* __restrict__ pred,
    float* __restrict__ rows) {
#pragma clang fp contract(off)
  const int g = blockIdx.x;
  const int b = g / NCLS;
  const int c1 = g % NCLS;                // class = c1 + 1
  const int tid = threadIdx.x;

  __shared__ unsigned pk_s[NTHR * NE];    // orderable score per element
  __shared__ unsigned long long red[2][8]; // per-wave maxima, dbl-buffered

  const float* bimg = boxes + (long long)b * NANCH * 4;
  const unsigned NEG_ORD = flipf(NEGF);

  float bx0[NE], by0[NE], bx1[NE], by1[NE], a2[NE];

#pragma unroll
  for (int k = 0; k < NE; ++k) {
    int i = tid + k * NTHR;
    float s = NEGF;
    float4 bv = make_float4(0.f, 0.f, 0.f, 0.f);
    if (i < NANCH) {
      float raw = scores_t
          ? scores_t[((long long)b * NCLS + c1) * NANCH + i]
          : pred[((long long)b * NANCH + i) * PRED_STRIDE + 1 + c1];
      if (raw > 0.5f) s = raw;            // mask, exactly as reference
      bv = *(const float4*)(bimg + (long long)i * 4);
    }
    bx0[k] = bv.x; by0[k] = bv.y; bx1[k] = bv.z; by1[k] = bv.w;
    a2[k] = fmaxf(bv.z - bv.x, 0.f) * fmaxf(bv.w - bv.y, 0.f);
    pk_s[tid + k * NTHR] = flipf(s);
  }
  __syncthreads();

  float* grow = rows + (long long)g * NMSMAX * 6;
  int par = 0;
  int pstop = NMSMAX;

  for (int p = 0; p < NMSMAX; ++p) {
    // --- block argmax: key = (orderable(score)<<32) | (0xFFFFFFFF - idx)
    unsigned long long m = 0ull;
#pragma unroll
    for (int k = 0; k < NE; ++k) {
      int i = tid + k * NTHR;
      unsigned long long v =
          ((unsigned long long)pk_s[i] << 32) | (unsigned)(0xFFFFFFFFu - (unsigned)i);
      m = (v > m) ? v : m;
    }
#pragma unroll
    for (int off = 32; off >= 1; off >>= 1) {
      unsigned long long o = __shfl_down(m, off);
      m = (o > m) ? o : m;
    }
    if ((tid & 63) == 0) red[par][tid >> 6] = m;
    __syncthreads();
    unsigned long long best = red[par][0];
#pragma unroll
    for (int wv = 1; wv < 8; ++wv) {
      unsigned long long v = red[par][wv];
      best = (v > best) ? v : best;
    }
    par ^= 1;

    unsigned se = (unsigned)(best >> 32);
    unsigned sbits = (se & 0x80000000u) ? (se ^ 0x80000000u) : ~se;
    float bscore = __uint_as_float(sbits);
    if (!(bscore > -5e29f)) { pstop = p; break; }  // ref: ok = s[best] > NEG*0.5

    unsigned bidx = 0xFFFFFFFFu - (unsigned)(best & 0xFFFFFFFFu);
    float4 bb = *(const float4*)(bimg + (long long)bidx * 4);

    if (tid == 0) {
      grow[p * 6 + 0] = (float)(c1 + 1);
      grow[p * 6 + 1] = bscore;
      grow[p * 6 + 2] = bb.x;
      grow[p * 6 + 3] = bb.y;
      grow[p * 6 + 4] = bb.z;
      grow[p * 6 + 5] = bb.w;
    }

    // --- suppress: exact replication of reference IoU expression tree
    float a1 = fmaxf(bb.z - bb.x, 0.f) * fmaxf(bb.w - bb.y, 0.f);
#pragma unroll
    for (int k = 0; k < NE; ++k) {
      float ix0 = fmaxf(bb.x, bx0[k]);
      float iy0 = fmaxf(bb.y, by0[k]);
      float ix1 = fminf(bb.z, bx1[k]);
      float iy1 = fminf(bb.w, by1[k]);
      float inter = fmaxf(ix1 - ix0, 0.f) * fmaxf(iy1 - iy0, 0.f);
      float uni = (a1 + a2[k]) - inter;
      float iou = inter / fmaxf(uni, 1e-8f);       // IEEE f32 divide
      if (iou > 0.45f) pk_s[tid + k * NTHR] = NEG_ORD;
    }
  }

  // zero rows past the early-exit point (ref multiplies by ok=0)
  for (int j = pstop * 6 + tid; j < NMSMAX * 6; j += NTHR) grow[j] = 0.f;
}

// ----------------------------------------------------------------- top-k ---
// Per image: 2000 rows -> bitonic sort 2048 packed keys desc -> top 200.
__global__ void topk_kernel(const float* __restrict__ rows,
                            float* __restrict__ out) {
  __shared__ unsigned long long key[2048];
  const int b = blockIdx.x;
  const int tid = threadIdx.x;  // 256 threads
  const float* rb = rows + (long long)b * (NCLS * NMSMAX) * 6;

  for (int e = tid; e < 2048; e += 256) {
    unsigned long long k = 0ull;  // padding sorts last (scores are >= 0)
    if (e < NCLS * NMSMAX) {
      float s = rb[e * 6 + 1];
      unsigned se = flipf(s);
      k = ((unsigned long long)se << 32) | (unsigned)(0xFFFFFFFFu - (unsigned)e);
    }
    key[e] = k;
  }
  __syncthreads();

  for (unsigned k2 = 2; k2 <= 2048; k2 <<= 1) {
    for (unsigned j = k2 >> 1; j > 0; j >>= 1) {
      for (unsigned t = tid; t < 1024; t += 256) {
        unsigned i = t + (t & ~(j - 1));
        unsigned l = i + j;
        bool up = ((i & k2) == 0);
        unsigned long long a = key[i], c = key[l];
        if (up ? (a < c) : (a > c)) { key[i] = c; key[l] = a; }
      }
      __syncthreads();
    }
  }

  if (tid < TOPK) {
    unsigned long long kk = key[tid];
    unsigned e = 0xFFFFFFFFu - (unsigned)(kk & 0xFFFFFFFFu);
    const float* src = rb + (long long)e * 6;
    float* dst = out + ((long long)b * TOPK + tid) * 6;
#pragma unroll
    for (int j = 0; j < 6; ++j) dst[j] = src[j];
  }
}

// ---------------------------------------------------------------- launch ---
extern "C" void kernel_launch(void* const* d_in, const int* in_sizes, int n_in,
                              void* d_out, int out_size, void* d_ws, size_t ws_size,
                              hipStream_t stream) {
  const float* pred = (const float*)d_in[0];
  float* out = (float*)d_out;
  float* ws = (float*)d_ws;

  const long long boxes_f = (long long)NB * NANCH * 4;           // 2,235,392
  const long long rows_f  = (long long)NB * NCLS * NMSMAX * 6;   //   768,000
  const long long st_f    = (long long)NB * NCLS * NANCH;        // 11,176,960

  float* boxes = ws;
  float* rows  = ws + boxes_f;
  float* st    = ws + boxes_f + rows_f;
  size_t need_st = (size_t)(boxes_f + rows_f + st_f) * sizeof(float);
  float* scores_t = (ws_size >= need_st) ? st : nullptr;

  long long total = (long long)NB * NANCH;
  int dgrid = (int)((total + 255) / 256);
  decode_kernel<<<dgrid, 256, 0, stream>>>(pred, boxes, scores_t);
  nms_kernel<<<NB * NCLS, NTHR, 0, stream>>>(boxes, scores_t, pred, rows);
  topk_kernel<<<NB, 256, 0, stream>>>(rows, out);
}

// Round 2
// 323.970 us; speedup vs baseline: 5.1469x; 5.1469x over previous
//
#include <hip/hip_runtime.h>
#include <math.h>

// SSD decode + per-class greedy NMS + per-image top-k for MI355X (gfx950).
//
// Exactness strategy (unchanged from the bit-exact round-1 kernel):
//  - fp contract OFF; every fp32 op individually rounded, same expression
//    tree as the reference -> identical bits
//  - exp via double (correctly-rounded fp32 exp)
//  - IEEE f32 divide kept for the IoU compare
//  - tie-breaks via packed u64 key (score desc, index asc)
//
// NMS algorithm change: greedy NMS == "scan candidates in descending
// (score, -idx) order, accept iff IoU <= thresh vs all previously accepted,
// stop at NMS_MAX". With this data only ~200-600 of ~4366 candidates get
// scanned, vs 100 full argmax+suppress sweeps over 9216 slots.
// Ordering is produced by monotone score-bucketing (2048 buckets) +
// exact within-bucket insertion sort on the full u64 key (total order ->
// deterministic despite atomic scatter).

#pragma clang fp contract(off)

#define NANCH 8732
#define NB 64
#define NCLS 20            // foreground classes (class ids 1..20)
#define NMSMAX 100
#define TOPK 200
#define PRED_STRIDE 33     // 21 conf + 4 loc + 4 anchor + 4 var
#define NTHR 512
#define NE 18              // ceil(8732/512)
#define NBUCK 2048
#define NEGF -1e30f

__device__ __forceinline__ unsigned flipf(float f) {
  unsigned u = __float_as_uint(f);
  return u ^ ((u >> 31) ? 0xFFFFFFFFu : 0x80000000u);
}

__device__ __forceinline__ float unflipf(unsigned se) {
  unsigned sbits = (se & 0x80000000u) ? (se ^ 0x80000000u) : ~se;
  return __uint_as_float(sbits);
}

// Monotone (non-strict) map score -> processing bucket (0 = highest scores).
// Only called for s > 0.5; any monotone map is CORRECT (within-bucket sort
// fixes exact order); this one is near-uniform for s ~ U(0.5, 1).
__device__ __forceinline__ int bucket_of(float s) {
  float t = (s - 0.5f) * 4096.0f;
  int b = (int)t;
  b = b < 0 ? 0 : (b > (NBUCK - 1) ? (NBUCK - 1) : b);
  return (NBUCK - 1) - b;
}

// ---------------------------------------------------------------- decode ---
__global__ void decode_kernel(const float* __restrict__ pred,
                              float* __restrict__ boxes,
                              float* __restrict__ scores_t) {
#pragma clang fp contract(off)
  long long idx = (long long)blockIdx.x * blockDim.x + threadIdx.x;
  if (idx >= (long long)NB * NANCH) return;
  int b = (int)(idx / NANCH);
  int n = (int)(idx % NANCH);
  const float* row = pred + idx * PRED_STRIDE;

  float l0 = row[21], l1 = row[22], l2 = row[23], l3 = row[24];
  float ax = row[25], ay = row[26], aw = row[27], ah = row[28];
  float v0 = row[29], v1 = row[30], v2 = row[31], v3 = row[32];

  float cx = (l0 * v0) * aw + ax;
  float cy = (l1 * v1) * ah + ay;
  float t2 = l2 * v2;
  float t3 = l3 * v3;
  float e2 = (float)exp((double)t2);
  float e3 = (float)exp((double)t3);
  float w = e2 * aw;
  float h = e3 * ah;
  float hw = 0.5f * w, hh = 0.5f * h;
  float xmin = (cx - hw) * 300.0f;
  float ymin = (cy - hh) * 300.0f;
  float xmax = (cx + hw) * 300.0f;
  float ymax = (cy + hh) * 300.0f;

  *(float4*)(boxes + idx * 4) = make_float4(xmin, ymin, xmax, ymax);

  if (scores_t) {
#pragma unroll
    for (int c = 0; c < NCLS; ++c) {
      scores_t[((long long)b * NCLS + c) * NANCH + n] = row[1 + c];
    }
  }
}

// ------------------------------------------------------------------- NMS ---
__global__ __launch_bounds__(NTHR) void nms_kernel(
    const float* __restrict__ boxes,
    const float* __restrict__ scores_t,   // may be null -> strided fallback
    const float* __restrict__ pred,
    float* __restrict__ rows) {
#pragma clang fp contract(off)
  const int g = blockIdx.x;
  const int b = g / NCLS;
  const int c1 = g % NCLS;                // class = c1 + 1
  const int tid = threadIdx.x;
  const int lane = tid & 63;
  const int wid = tid >> 6;

  __shared__ unsigned long long keys[NANCH];       // 69,856 B
  __shared__ __align__(16) unsigned off[NBUCK];    //  8,192 B (reused as box stage)
  __shared__ unsigned wsum[8];
  __shared__ int nacc_s;

  const float* bimg = boxes + (long long)b * NANCH * 4;
  float* grow = rows + (long long)g * NMSMAX * 6;

  // ---- phase A: histogram of candidate buckets -------------------------
  for (int q = 0; q < NBUCK / NTHR; ++q) off[tid + q * NTHR] = 0u;
  __syncthreads();

#pragma unroll
  for (int k = 0; k < NE; ++k) {
    int i = tid + (k << 9);
    if (i < NANCH) {
      float s = scores_t
          ? scores_t[((long long)b * NCLS + c1) * NANCH + i]
          : pred[((long long)b * NANCH + i) * PRED_STRIDE + 1 + c1];
      if (s > 0.5f) atomicAdd(&off[bucket_of(s)], 1u);
    }
  }
  __syncthreads();

  // ---- block exclusive scan over the 2048 counts -----------------------
  {
    unsigned v0 = off[(tid << 2) + 0], v1 = off[(tid << 2) + 1];
    unsigned v2 = off[(tid << 2) + 2], v3 = off[(tid << 2) + 3];
    unsigned ls = v0 + v1 + v2 + v3;
    unsigned x = ls;
#pragma unroll
    for (int d = 1; d < 64; d <<= 1) {
      unsigned y = __shfl_up(x, d);
      if (lane >= d) x += y;
    }
    if (lane == 63) wsum[wid] = x;
    __syncthreads();
    unsigned wbase = 0;
    for (int w = 0; w < wid; ++w) wbase += wsum[w];
    unsigned base = wbase + x - ls;   // exclusive prefix for this thread
    off[(tid << 2) + 0] = base;
    off[(tid << 2) + 1] = base + v0;
    off[(tid << 2) + 2] = base + v0 + v1;
    off[(tid << 2) + 3] = base + v0 + v1 + v2;
  }
  __syncthreads();

  // ---- phase B: scatter packed keys into bucket-ordered array ----------
#pragma unroll
  for (int k = 0; k < NE; ++k) {
    int i = tid + (k << 9);
    if (i < NANCH) {
      float s = scores_t
          ? scores_t[((long long)b * NCLS + c1) * NANCH + i]
          : pred[((long long)b * NANCH + i) * PRED_STRIDE + 1 + c1];
      if (s > 0.5f) {
        unsigned long long key = ((unsigned long long)flipf(s) << 32) |
                                 (unsigned)(0xFFFFFFFFu - (unsigned)i);
        unsigned slot = atomicAdd(&off[bucket_of(s)], 1u);
        keys[slot] = key;
      }
    }
  }
  __syncthreads();   // off[] now holds END offsets; end[b] == start[b+1]

  // ---- phase C: exact within-bucket sort (desc by full u64 key) --------
  for (int q = 0; q < NBUCK / NTHR; ++q) {
    int bk = tid * (NBUCK / NTHR) + q;
    int st = bk ? (int)off[bk - 1] : 0;
    int en = (int)off[bk];
    for (int i = st + 1; i < en; ++i) {
      unsigned long long k = keys[i];
      int j = i - 1;
      while (j >= st && keys[j] < k) { keys[j + 1] = keys[j]; --j; }
      keys[j + 1] = k;
    }
  }
  __syncthreads();

  const int ncand = (int)off[NBUCK - 1];
  __syncthreads();

  // ---- stage first 512 candidate boxes (reuse off[] as float4 stage) ---
  float4* stage = (float4*)off;
  if (tid < 512 && tid < ncand) {
    unsigned bidx = 0xFFFFFFFFu - (unsigned)(keys[tid] & 0xFFFFFFFFu);
    stage[tid] = *(const float4*)(bimg + (long long)bidx * 4);
  }
  __syncthreads();

  // ---- phase D: serial greedy scan by wave 0 ---------------------------
  if (wid == 0) {
    float4 aLo = make_float4(0.f, 0.f, 0.f, 0.f);
    float4 aHi = make_float4(0.f, 0.f, 0.f, 0.f);
    float arLo = 0.f, arHi = 0.f;   // precomputed accepted areas (a1)
    int nacc = 0;

    for (int s = 0; s < ncand; ++s) {
      if (nacc >= NMSMAX) break;
      if ((s & 511) == 0 && s) {
        // restage next 512 boxes (single wave: no barrier needed)
#pragma unroll
        for (int r = 0; r < 8; ++r) {
          int slot = s + lane + (r << 6);
          if (slot < ncand) {
            unsigned bidx = 0xFFFFFFFFu - (unsigned)(keys[slot] & 0xFFFFFFFFu);
            stage[slot & 511] = *(const float4*)(bimg + (long long)bidx * 4);
          }
        }
      }
      unsigned long long kk = keys[s];          // uniform addr -> broadcast
      float4 cb = stage[s & 511];               // uniform addr -> broadcast
      // a2 = area(candidate), same expression as reference
      float ca = fmaxf(cb.z - cb.x, 0.f) * fmaxf(cb.w - cb.y, 0.f);

      bool su = false;
      if (lane < nacc) {
        float ix0 = fmaxf(aLo.x, cb.x), iy0 = fmaxf(aLo.y, cb.y);
        float ix1 = fminf(aLo.z, cb.z), iy1 = fminf(aLo.w, cb.w);
        float inter = fmaxf(ix1 - ix0, 0.f) * fmaxf(iy1 - iy0, 0.f);
        float den = fmaxf(arLo + ca - inter, 1e-8f);
        su = (inter / den) > 0.45f;
      }
      if (lane + 64 < nacc) {
        float ix0 = fmaxf(aHi.x, cb.x), iy0 = fmaxf(aHi.y, cb.y);
        float ix1 = fminf(aHi.z, cb.z), iy1 = fminf(aHi.w, cb.w);
        float inter = fmaxf(ix1 - ix0, 0.f) * fmaxf(iy1 - iy0, 0.f);
        float den = fmaxf(arHi + ca - inter, 1e-8f);
        su = su || ((inter / den) > 0.45f);
      }
      if (!__any(su)) {
        if (lane == (nacc & 63)) {
          if (nacc < 64) { aLo = cb; arLo = ca; }
          else           { aHi = cb; arHi = ca; }
        }
        if (lane == 0) {
          float* gr = grow + nacc * 6;
          gr[0] = (float)(c1 + 1);
          gr[1] = unflipf((unsigned)(kk >> 32));
          gr[2] = cb.x; gr[3] = cb.y; gr[4] = cb.z; gr[5] = cb.w;
        }
        ++nacc;
      }
    }
    if (lane == 0) nacc_s = nacc;
  }
  __syncthreads();

  // ---- zero-fill rows past the accepted count (ref: ok = 0 rows) -------
  for (int j = nacc_s * 6 + tid; j < NMSMAX * 6; j += NTHR) grow[j] = 0.f;
}

// ----------------------------------------------------------------- top-k ---
__global__ void topk_kernel(const float* __restrict__ rows,
                            float* __restrict__ out) {
  __shared__ unsigned long long key[2048];
  const int b = blockIdx.x;
  const int tid = threadIdx.x;  // 256 threads
  const float* rb = rows + (long long)b * (NCLS * NMSMAX) * 6;

  for (int e = tid; e < 2048; e += 256) {
    unsigned long long k = 0ull;  // padding sorts last (scores are >= 0)
    if (e < NCLS * NMSMAX) {
      float s = rb[e * 6 + 1];
      unsigned se = flipf(s);
      k = ((unsigned long long)se << 32) | (unsigned)(0xFFFFFFFFu - (unsigned)e);
    }
    key[e] = k;
  }
  __syncthreads();

  for (unsigned k2 = 2; k2 <= 2048; k2 <<= 1) {
    for (unsigned j = k2 >> 1; j > 0; j >>= 1) {
      for (unsigned t = tid; t < 1024; t += 256) {
        unsigned i = t + (t & ~(j - 1));
        unsigned l = i + j;
        bool up = ((i & k2) == 0);
        unsigned long long a = key[i], c = key[l];
        if (up ? (a < c) : (a > c)) { key[i] = c; key[l] = a; }
      }
      __syncthreads();
    }
  }

  if (tid < TOPK) {
    unsigned long long kk = key[tid];
    unsigned e = 0xFFFFFFFFu - (unsigned)(kk & 0xFFFFFFFFu);
    const float* src = rb + (long long)e * 6;
    float* dst = out + ((long long)b * TOPK + tid) * 6;
#pragma unroll
    for (int j = 0; j < 6; ++j) dst[j] = src[j];
  }
}

// ---------------------------------------------------------------- launch ---
extern "C" void kernel_launch(void* const* d_in, const int* in_sizes, int n_in,
                              void* d_out, int out_size, void* d_ws, size_t ws_size,
                              hipStream_t stream) {
  const float* pred = (const float*)d_in[0];
  float* out = (float*)d_out;
  float* ws = (float*)d_ws;

  const long long boxes_f = (long long)NB * NANCH * 4;           // 2,235,392
  const long long rows_f  = (long long)NB * NCLS * NMSMAX * 6;   //   768,000
  const long long st_f    = (long long)NB * NCLS * NANCH;        // 11,176,960

  float* boxes = ws;
  float* rows  = ws + boxes_f;
  float* st    = ws + boxes_f + rows_f;
  size_t need_st = (size_t)(boxes_f + rows_f + st_f) * sizeof(float);
  float* scores_t = (ws_size >= need_st) ? st : nullptr;

  long long total = (long long)NB * NANCH;
  int dgrid = (int)((total + 255) / 256);
  decode_kernel<<<dgrid, 256, 0, stream>>>(pred, boxes, scores_t);
  nms_kernel<<<NB * NCLS, NTHR, 0, stream>>>(boxes, scores_t, pred, rows);
  topk_kernel<<<NB, 256, 0, stream>>>(rows, out);
}

// Round 3
// 278.920 us; speedup vs baseline: 5.9782x; 1.1615x over previous
//
#include <hip/hip_runtime.h>
#include <math.h>

// SSD decode + per-class greedy NMS + per-image top-k for MI355X (gfx950).
//
// Exactness strategy (bit-exact vs the fp32 reference, absmax 0.0 in r1/r2):
//  - fp contract OFF; every fp32 op individually rounded, same expression
//    tree as the reference
//  - exp via double (correctly-rounded fp32 exp)
//  - IoU compare: the reference computes q = RN(inter/den), q > 0.45f.
//    We use (double)inter > THR*(double)den with THR = (double)0.45f + 2^-26
//    (= the rounding midpoint above 0.45f). Both inter and den are exact
//    f32 values; THR*den fits in 50 mantissa bits -> product exact; at the
//    exact midpoint RN ties-to-even gives 0.45f (mantissa even) so q > c is
//    false, and our strict '>' is also false. Bit-equivalent, ~8 fewer
//    instructions than the IEEE divide.
//  - tie-breaks via packed u64 key (score desc, index asc), matching
//    jnp.argmax / lax.top_k.
//
// NMS: greedy NMS == scan candidates in descending (score,-idx) order,
// accept iff IoU<=thr vs all previous accepts, stop at 100. Candidates are
// ordered by 2048-bucket counting sort + exact within-bucket insertion sort.
// The scan is chunked 64-wide: parallel pre-test vs prior accepts, then a
// serial in-wave resolve (ballot/ffs/readlane) for intra-chunk ordering.

#pragma clang fp contract(off)

#define NANCH 8732
#define NB 64
#define NCLS 20            // foreground classes (class ids 1..20)
#define NMSMAX 100
#define TOPK 200
#define PRED_STRIDE 33     // 21 conf + 4 loc + 4 anchor + 4 var
#define NTHR 512
#define NE 18              // ceil(8732/512)
#define NBUCK 2048
#define NEGF -1e30f

__device__ __forceinline__ unsigned flipf(float f) {
  unsigned u = __float_as_uint(f);
  return u ^ ((u >> 31) ? 0xFFFFFFFFu : 0x80000000u);
}

__device__ __forceinline__ float unflipf(unsigned se) {
  unsigned sbits = (se & 0x80000000u) ? (se ^ 0x80000000u) : ~se;
  return __uint_as_float(sbits);
}

// Monotone map score -> processing bucket (0 = highest). Any monotone map is
// correct (within-bucket sort fixes exact order); near-uniform for U(0.5,1).
__device__ __forceinline__ int bucket_of(float s) {
  float t = (s - 0.5f) * 4096.0f;
  int b = (int)t;
  b = b < 0 ? 0 : (b > (NBUCK - 1) ? (NBUCK - 1) : b);
  return (NBUCK - 1) - b;
}

// exact IoU>0.45f predicate (see header comment)
__device__ __forceinline__ bool iou_gt(float inter, float den) {
  const double THR = (double)0.45f + 0x1.0p-26;
  return (double)inter > THR * (double)den;
}

__device__ __forceinline__ float rdlanef(float v, int l) {
  return __uint_as_float(__builtin_amdgcn_readlane(__float_as_uint(v), l));
}

// ---------------------------------------------------------------- decode ---
__global__ void decode_kernel(const float* __restrict__ pred,
                              float* __restrict__ boxes,
                              float* __restrict__ scores_t) {
#pragma clang fp contract(off)
  int n = blockIdx.x * blockDim.x + threadIdx.x;
  int b = blockIdx.y;
  if (n >= NANCH) return;
  long long idx = (long long)b * NANCH + n;
  const float* row = pred + idx * PRED_STRIDE;

  float l0 = row[21], l1 = row[22], l2 = row[23], l3 = row[24];
  float ax = row[25], ay = row[26], aw = row[27], ah = row[28];
  float v0 = row[29], v1 = row[30], v2 = row[31], v3 = row[32];

  float cx = (l0 * v0) * aw + ax;
  float cy = (l1 * v1) * ah + ay;
  float e2 = (float)exp((double)(l2 * v2));
  float e3 = (float)exp((double)(l3 * v3));
  float w = e2 * aw;
  float h = e3 * ah;
  float hw = 0.5f * w, hh = 0.5f * h;
  float xmin = (cx - hw) * 300.0f;
  float ymin = (cy - hh) * 300.0f;
  float xmax = (cx + hw) * 300.0f;
  float ymax = (cy + hh) * 300.0f;

  *(float4*)(boxes + idx * 4) = make_float4(xmin, ymin, xmax, ymax);

  if (scores_t) {
#pragma unroll
    for (int c = 0; c < NCLS; ++c) {
      scores_t[((long long)b * NCLS + c) * NANCH + n] = row[1 + c];
    }
  }
}

// ------------------------------------------------------------------- NMS ---
__global__ __launch_bounds__(NTHR) void nms_kernel(
    const float* __restrict__ boxes,
    const float* __restrict__ scores_t,   // may be null -> strided fallback
    const float* __restrict__ pred,
    float* __restrict__ rows) {
#pragma clang fp contract(off)
  const int g = blockIdx.x;
  const int b = g / NCLS;
  const int c1 = g % NCLS;                // class = c1 + 1
  const int tid = threadIdx.x;
  const int lane = tid & 63;
  const int wid = tid >> 6;

  __shared__ unsigned long long keys[NANCH];     // 69,856 B
  __shared__ unsigned off[NBUCK];                //  8,192 B
  __shared__ unsigned wsum[8];
  __shared__ float4 accb[NMSMAX];                //  1,600 B
  __shared__ float acca[NMSMAX];                 //    400 B
  __shared__ int nacc_s;

  const float* bimg = boxes + (long long)b * NANCH * 4;
  float* grow = rows + (long long)g * NMSMAX * 6;

  // ---- phase A: load scores once, histogram candidate buckets ----------
  for (int q = 0; q < NBUCK / NTHR; ++q) off[tid + q * NTHR] = 0u;
  __syncthreads();

  unsigned sflip[NE];
  short bkt[NE];
#pragma unroll
  for (int k = 0; k < NE; ++k) {
    int i = tid + (k << 9);
    bkt[k] = -1;
    if (i < NANCH) {
      float s = scores_t
          ? scores_t[((long long)b * NCLS + c1) * NANCH + i]
          : pred[((long long)b * NANCH + i) * PRED_STRIDE + 1 + c1];
      if (s > 0.5f) {
        int bb = bucket_of(s);
        bkt[k] = (short)bb;
        sflip[k] = flipf(s);
        atomicAdd(&off[bb], 1u);
      }
    }
  }
  __syncthreads();

  // ---- block exclusive scan over the 2048 counts -----------------------
  {
    unsigned v0 = off[(tid << 2) + 0], v1 = off[(tid << 2) + 1];
    unsigned v2 = off[(tid << 2) + 2], v3 = off[(tid << 2) + 3];
    unsigned ls = v0 + v1 + v2 + v3;
    unsigned x = ls;
#pragma unroll
    for (int d = 1; d < 64; d <<= 1) {
      unsigned y = __shfl_up(x, d);
      if (lane >= d) x += y;
    }
    if (lane == 63) wsum[wid] = x;
    __syncthreads();
    unsigned wbase = 0;
    for (int w = 0; w < wid; ++w) wbase += wsum[w];
    unsigned base = wbase + x - ls;
    off[(tid << 2) + 0] = base;
    off[(tid << 2) + 1] = base + v0;
    off[(tid << 2) + 2] = base + v0 + v1;
    off[(tid << 2) + 3] = base + v0 + v1 + v2;
  }
  __syncthreads();

  // ---- phase B: scatter packed keys (scores from registers) ------------
#pragma unroll
  for (int k = 0; k < NE; ++k) {
    if (bkt[k] >= 0) {
      int i = tid + (k << 9);
      unsigned long long key = ((unsigned long long)sflip[k] << 32) |
                               (unsigned)(0xFFFFFFFFu - (unsigned)i);
      unsigned slot = atomicAdd(&off[(int)bkt[k]], 1u);
      keys[slot] = key;
    }
  }
  __syncthreads();   // off[] now holds END offsets; end[b] == start[b+1]

  // ---- phase C: exact within-bucket sort (desc by full u64 key) --------
  for (int q = 0; q < NBUCK / NTHR; ++q) {
    int bk = tid * (NBUCK / NTHR) + q;
    int st = bk ? (int)off[bk - 1] : 0;
    int en = (int)off[bk];
    for (int i = st + 1; i < en; ++i) {
      unsigned long long k = keys[i];
      int j = i - 1;
      while (j >= st && keys[j] < k) { keys[j + 1] = keys[j]; --j; }
      keys[j + 1] = k;
    }
  }
  __syncthreads();

  const int ncand = (int)off[NBUCK - 1];

  // ---- phase D: chunked greedy scan (wave 0) ---------------------------
  if (wid == 0 && ncand > 0) {
    const float fcls = (float)(c1 + 1);
    int nacc = 0;
    const int nchunk = (ncand + 63) >> 6;

    // prefetch chunk 0
    int slot0 = lane < ncand ? lane : 0;
    unsigned long long kcur = keys[slot0];
    float4 cbv;
    {
      unsigned bidx = 0xFFFFFFFFu - (unsigned)(kcur & 0xFFFFFFFFu);
      cbv = *(const float4*)(bimg + (long long)bidx * 4);
    }

    for (int c = 0; c < nchunk && nacc < NMSMAX; ++c) {
      // prefetch next chunk (keys -> gathered boxes), hidden under compute
      unsigned long long knxt = 0ull;
      float4 cbn = make_float4(0.f, 0.f, 0.f, 0.f);
      if (c + 1 < nchunk) {
        int sl = ((c + 1) << 6) + lane;
        int cl = sl < ncand ? sl : 0;
        knxt = keys[cl];
        unsigned bidx = 0xFFFFFFFFu - (unsigned)(knxt & 0xFFFFFFFFu);
        cbn = *(const float4*)(bimg + (long long)bidx * 4);
      }

      const float4 cb = cbv;
      const float ca = fmaxf(cb.z - cb.x, 0.f) * fmaxf(cb.w - cb.y, 0.f);
      bool su = ((c << 6) + lane) >= ncand;   // invalid lanes start dead

      // pre-test vs all accepts made before this chunk
      for (int j = 0; j < nacc; ++j) {
        float4 ab = accb[j];                  // uniform addr -> broadcast
        float aa = acca[j];
        float ix0 = fmaxf(ab.x, cb.x), iy0 = fmaxf(ab.y, cb.y);
        float ix1 = fminf(ab.z, cb.z), iy1 = fminf(ab.w, cb.w);
        float inter = fmaxf(ix1 - ix0, 0.f) * fmaxf(iy1 - iy0, 0.f);
        float den = fmaxf((aa + ca) - inter, 1e-8f);
        su = su || iou_gt(inter, den);
      }

      // serial resolve: accept lowest live lane, suppress vs it, repeat
      unsigned long long live = __ballot(!su);
      while (live && nacc < NMSMAX) {
        int l = __ffsll(live) - 1;
        float bx = rdlanef(cb.x, l), by = rdlanef(cb.y, l);
        float bz = rdlanef(cb.z, l), bw = rdlanef(cb.w, l);
        unsigned khi = __builtin_amdgcn_readlane((unsigned)(kcur >> 32), l);
        float aa = fmaxf(bz - bx, 0.f) * fmaxf(bw - by, 0.f);
        if (lane == 0) {
          float* gr = grow + nacc * 6;
          gr[0] = fcls;
          gr[1] = unflipf(khi);
          gr[2] = bx; gr[3] = by; gr[4] = bz; gr[5] = bw;
          accb[nacc] = make_float4(bx, by, bz, bw);
          acca[nacc] = aa;
        }
        ++nacc;
        // incremental suppression vs the new accept
        float ix0 = fmaxf(bx, cb.x), iy0 = fmaxf(by, cb.y);
        float ix1 = fminf(bz, cb.z), iy1 = fminf(bw, cb.w);
        float inter = fmaxf(ix1 - ix0, 0.f) * fmaxf(iy1 - iy0, 0.f);
        float den = fmaxf((aa + ca) - inter, 1e-8f);
        su = su || iou_gt(inter, den) || (lane == l);
        live = __ballot(!su);
      }

      kcur = knxt; cbv = cbn;
    }
    if (lane == 0) nacc_s = nacc;
  } else if (tid == 0 && ncand == 0) {
    nacc_s = 0;
  }
  __syncthreads();

  // ---- zero-fill rows past the accepted count (ref: ok = 0 rows) -------
  for (int j = nacc_s * 6 + tid; j < NMSMAX * 6; j += NTHR) grow[j] = 0.f;
}

// ----------------------------------------------------------------- top-k ---
__global__ __launch_bounds__(512) void topk_kernel(const float* __restrict__ rows,
                                                   float* __restrict__ out) {
  __shared__ unsigned long long key[2048];
  const int b = blockIdx.x;
  const int tid = threadIdx.x;  // 512 threads
  const float* rb = rows + (long long)b * (NCLS * NMSMAX) * 6;

  for (int e = tid; e < 2048; e += 512) {
    unsigned long long k = 0ull;  // padding sorts last (scores are >= 0)
    if (e < NCLS * NMSMAX) {
      float s = rb[e * 6 + 1];
      unsigned se = flipf(s);
      k = ((unsigned long long)se << 32) | (unsigned)(0xFFFFFFFFu - (unsigned)e);
    }
    key[e] = k;
  }
  __syncthreads();

  for (unsigned k2 = 2; k2 <= 2048; k2 <<= 1) {
    for (unsigned j = k2 >> 1; j > 0; j >>= 1) {
      for (unsigned t = tid; t < 1024; t += 512) {
        unsigned i = t + (t & ~(j - 1));
        unsigned l = i + j;
        bool up = ((i & k2) == 0);
        unsigned long long a = key[i], c = key[l];
        if (up ? (a < c) : (a > c)) { key[i] = c; key[l] = a; }
      }
      __syncthreads();
    }
  }

  if (tid < TOPK) {
    unsigned long long kk = key[tid];
    unsigned e = 0xFFFFFFFFu - (unsigned)(kk & 0xFFFFFFFFu);
    const float* src = rb + (long long)e * 6;
    float* dst = out + ((long long)b * TOPK + tid) * 6;
#pragma unroll
    for (int j = 0; j < 6; ++j) dst[j] = src[j];
  }
}

// ---------------------------------------------------------------- launch ---
extern "C" void kernel_launch(void* const* d_in, const int* in_sizes, int n_in,
                              void* d_out, int out_size, void* d_ws, size_t ws_size,
                              hipStream_t stream) {
  const float* pred = (const float*)d_in[0];
  float* out = (float*)d_out;
  float* ws = (float*)d_ws;

  const long long boxes_f = (long long)NB * NANCH * 4;           // 2,235,392
  const long long rows_f  = (long long)NB * NCLS * NMSMAX * 6;   //   768,000
  const long long st_f    = (long long)NB * NCLS * NANCH;        // 11,176,960

  float* boxes = ws;
  float* rows  = ws + boxes_f;
  float* st    = ws + boxes_f + rows_f;
  size_t need_st = (size_t)(boxes_f + rows_f + st_f) * sizeof(float);
  float* scores_t = (ws_size >= need_st) ? st : nullptr;

  dim3 dgrid((NANCH + 255) / 256, NB);
  decode_kernel<<<dgrid, 256, 0, stream>>>(pred, boxes, scores_t);
  nms_kernel<<<NB * NCLS, NTHR, 0, stream>>>(boxes, scores_t, pred, rows);
  topk_kernel<<<NB, 512, 0, stream>>>(rows, out);
}

// Round 4
// 240.321 us; speedup vs baseline: 6.9384x; 1.1606x over previous
//
#include <hip/hip_runtime.h>
#include <math.h>

// SSD decode + per-class greedy NMS + per-image top-k for MI355X (gfx950).
//
// Exactness strategy (bit-exact vs the fp32 reference, absmax 0.0 r1-r3):
//  - fp contract OFF; every fp32 op individually rounded, same expression
//    tree as the reference
//  - exp via double (correctly-rounded fp32 exp)
//  - IoU compare: reference computes q = RN(inter/den), q > 0.45f. We use
//    (double)inter > THR*(double)den with THR = (double)0.45f + 2^-26 (the
//    rounding midpoint above 0.45f). inter/den are exact f32; THR*den fits
//    50 mantissa bits -> exact; midpoint ties round to even = 0.45f so both
//    forms say false. Bit-equivalent.
//  - tie-breaks via packed u64 key (score desc, index asc).
//
// Pipeline (4 kernels):
//  1. decode: LDS tile transpose -> coalesced boxes + scores_t writes
//     (fixes the 35KB-strided 4B score writes that dominated r2/r3).
//  2. sort: per (b,c) block, 2048-bucket counting sort + exact within-bucket
//     insertion sort; writes sorted u16 candidate indices + ncand to global.
//  3. scan: one 64-thread block per (b,c) (2KB LDS -> many resident serial
//     scans per CU); chunked greedy accept identical to r3 phase D.
//  4. topk: per-image bitonic top-200.

#pragma clang fp contract(off)

#define NANCH 8732
#define NB 64
#define NCLS 20            // foreground classes (class ids 1..20)
#define NMSMAX 100
#define TOPK 200
#define PRED_STRIDE 33     // 21 conf + 4 loc + 4 anchor + 4 var
#define NTHR 512
#define NE 18              // ceil(8732/512)
#define NBUCK 2048
#define NEGF -1e30f
#define DTILE 64

__device__ __forceinline__ unsigned flipf(float f) {
  unsigned u = __float_as_uint(f);
  return u ^ ((u >> 31) ? 0xFFFFFFFFu : 0x80000000u);
}

__device__ __forceinline__ float unflipf(unsigned se) {
  unsigned sbits = (se & 0x80000000u) ? (se ^ 0x80000000u) : ~se;
  return __uint_as_float(sbits);
}

// Monotone map score -> processing bucket (0 = highest). Any monotone map is
// correct (within-bucket sort fixes exact order); near-uniform for U(0.5,1).
__device__ __forceinline__ int bucket_of(float s) {
  float t = (s - 0.5f) * 4096.0f;
  int b = (int)t;
  b = b < 0 ? 0 : (b > (NBUCK - 1) ? (NBUCK - 1) : b);
  return (NBUCK - 1) - b;
}

// exact IoU>0.45f predicate (see header comment)
__device__ __forceinline__ bool iou_gt(float inter, float den) {
  const double THR = (double)0.45f + 0x1.0p-26;
  return (double)inter > THR * (double)den;
}

__device__ __forceinline__ float rdlanef(float v, int l) {
  return __uint_as_float(__builtin_amdgcn_readlane(__float_as_uint(v), l));
}

// ---------------------------------------------------------------- decode ---
// 256 threads handle 64 anchors of one image: coalesced read of the 64x33
// pred rows into LDS, decode by wave 0, transposed coalesced score writes.
__global__ __launch_bounds__(256) void decode_kernel(
    const float* __restrict__ pred,
    float* __restrict__ boxes,
    float* __restrict__ scores_t) {
#pragma clang fp contract(off)
  const int b = blockIdx.y;
  const int n0 = blockIdx.x * DTILE;
  const int na = (NANCH - n0) < DTILE ? (NANCH - n0) : DTILE;
  const int tid = threadIdx.x;
  const int l = tid & 63;

  __shared__ float lds[DTILE * PRED_STRIDE];   // 8448 B

  const float* src = pred + ((long long)b * NANCH + n0) * PRED_STRIDE;
  const int tot = na * PRED_STRIDE;
  for (int e = tid; e < tot; e += 256) lds[e] = src[e];
  __syncthreads();

  if (tid < 64 && l < na) {
    const float* row = lds + l * PRED_STRIDE;
    float l0 = row[21], l1 = row[22], l2 = row[23], l3 = row[24];
    float ax = row[25], ay = row[26], aw = row[27], ah = row[28];
    float v0 = row[29], v1 = row[30], v2 = row[31], v3 = row[32];

    float cx = (l0 * v0) * aw + ax;
    float cy = (l1 * v1) * ah + ay;
    float e2 = (float)exp((double)(l2 * v2));
    float e3 = (float)exp((double)(l3 * v3));
    float w = e2 * aw;
    float h = e3 * ah;
    float hw = 0.5f * w, hh = 0.5f * h;
    float xmin = (cx - hw) * 300.0f;
    float ymin = (cy - hh) * 300.0f;
    float xmax = (cx + hw) * 300.0f;
    float ymax = (cy + hh) * 300.0f;
    *(float4*)(boxes + ((long long)b * NANCH + n0 + l) * 4) =
        make_float4(xmin, ymin, xmax, ymax);
  }

  if (scores_t) {
#pragma unroll
    for (int it = 0; it < 5; ++it) {
      int c = (tid >> 6) + (it << 2);          // 0..19 across 5 iters
      if (l < na) {
        scores_t[((long long)b * NCLS + c) * NANCH + n0 + l] =
            lds[l * PRED_STRIDE + 1 + c];
      }
    }
  }
}

// -------------------------------------------------------------------- sort ---
// Per (b,c): counting sort by 2048 score buckets + exact within-bucket
// insertion sort on full u64 keys; writes sorted u16 indices + ncand.
__global__ __launch_bounds__(NTHR) void sort_kernel(
    const float* __restrict__ scores_t,
    unsigned short* __restrict__ sidx,
    int* __restrict__ ncand_g) {
#pragma clang fp contract(off)
  const int g = blockIdx.x;
  const int b = g / NCLS;
  const int c1 = g % NCLS;
  const int tid = threadIdx.x;
  const int lane = tid & 63;
  const int wid = tid >> 6;

  __shared__ unsigned long long keys[NANCH];     // 69,856 B
  __shared__ unsigned off[NBUCK];                //  8,192 B
  __shared__ unsigned wsum[8];

  const float* srow = scores_t + ((long long)b * NCLS + c1) * NANCH;

  // ---- phase A: load scores once, histogram candidate buckets ----------
  for (int q = 0; q < NBUCK / NTHR; ++q) off[tid + q * NTHR] = 0u;
  __syncthreads();

  unsigned sflip[NE];
  short bkt[NE];
#pragma unroll
  for (int k = 0; k < NE; ++k) {
    int i = tid + (k << 9);
    bkt[k] = -1;
    if (i < NANCH) {
      float s = srow[i];
      if (s > 0.5f) {
        int bb = bucket_of(s);
        bkt[k] = (short)bb;
        sflip[k] = flipf(s);
        atomicAdd(&off[bb], 1u);
      }
    }
  }
  __syncthreads();

  // ---- block exclusive scan over the 2048 counts -----------------------
  {
    unsigned v0 = off[(tid << 2) + 0], v1 = off[(tid << 2) + 1];
    unsigned v2 = off[(tid << 2) + 2], v3 = off[(tid << 2) + 3];
    unsigned ls = v0 + v1 + v2 + v3;
    unsigned x = ls;
#pragma unroll
    for (int d = 1; d < 64; d <<= 1) {
      unsigned y = __shfl_up(x, d);
      if (lane >= d) x += y;
    }
    if (lane == 63) wsum[wid] = x;
    __syncthreads();
    unsigned wbase = 0;
    for (int w = 0; w < wid; ++w) wbase += wsum[w];
    unsigned base = wbase + x - ls;
    off[(tid << 2) + 0] = base;
    off[(tid << 2) + 1] = base + v0;
    off[(tid << 2) + 2] = base + v0 + v1;
    off[(tid << 2) + 3] = base + v0 + v1 + v2;
  }
  __syncthreads();

  // ---- phase B: scatter packed keys (scores from registers) ------------
#pragma unroll
  for (int k = 0; k < NE; ++k) {
    if (bkt[k] >= 0) {
      int i = tid + (k << 9);
      unsigned long long key = ((unsigned long long)sflip[k] << 32) |
                               (unsigned)(0xFFFFFFFFu - (unsigned)i);
      unsigned slot = atomicAdd(&off[(int)bkt[k]], 1u);
      keys[slot] = key;
    }
  }
  __syncthreads();   // off[] now holds END offsets; end[b] == start[b+1]

  // ---- phase C: exact within-bucket sort (desc by full u64 key) --------
  for (int q = 0; q < NBUCK / NTHR; ++q) {
    int bk = tid * (NBUCK / NTHR) + q;
    int st = bk ? (int)off[bk - 1] : 0;
    int en = (int)off[bk];
    for (int i = st + 1; i < en; ++i) {
      unsigned long long k = keys[i];
      int j = i - 1;
      while (j >= st && keys[j] < k) { keys[j + 1] = keys[j]; --j; }
      keys[j + 1] = k;
    }
  }
  __syncthreads();

  const int ncand = (int)off[NBUCK - 1];

  // ---- write sorted candidate indices (u16) ----------------------------
  unsigned short* sg = sidx + (long long)g * NANCH;
  for (int s = tid; s < ncand; s += NTHR) {
    sg[s] = (unsigned short)(0xFFFFFFFFu - (unsigned)(keys[s] & 0xFFFFFFFFu));
  }
  if (tid == 0) ncand_g[g] = ncand;
}

// -------------------------------------------------------------------- scan ---
// One wave per (b,c): chunked greedy accept, identical logic to r3 phase D.
__global__ __launch_bounds__(64) void scan_kernel(
    const float* __restrict__ boxes,
    const float* __restrict__ scores_t,
    const unsigned short* __restrict__ sidx,
    const int* __restrict__ ncand_g,
    float* __restrict__ rows) {
#pragma clang fp contract(off)
  const int g = blockIdx.x;
  const int b = g / NCLS;
  const int c1 = g % NCLS;
  const int lane = threadIdx.x;

  __shared__ float4 accb[NMSMAX];    // 1600 B
  __shared__ float acca[NMSMAX];     //  400 B

  const float* bimg = boxes + (long long)b * NANCH * 4;
  const float* srow = scores_t + ((long long)b * NCLS + c1) * NANCH;
  const unsigned short* sg = sidx + (long long)g * NANCH;
  float* grow = rows + (long long)g * NMSMAX * 6;

  const int ncand = ncand_g[g];
  int nacc = 0;

  if (ncand > 0) {
    const float fcls = (float)(c1 + 1);
    const int nchunk = (ncand + 63) >> 6;

    // prefetch chunk 0
    int cl0 = lane < ncand ? lane : ncand - 1;
    unsigned id0 = sg[cl0];
    float4 cbv = *(const float4*)(bimg + (long long)id0 * 4);
    float scv = srow[id0];

    for (int c = 0; c < nchunk && nacc < NMSMAX; ++c) {
      // prefetch next chunk, hidden under compute
      float4 cbn = make_float4(0.f, 0.f, 0.f, 0.f);
      float scn = 0.f;
      if (c + 1 < nchunk) {
        int sl = ((c + 1) << 6) + lane;
        int cl = sl < ncand ? sl : ncand - 1;
        unsigned id = sg[cl];
        cbn = *(const float4*)(bimg + (long long)id * 4);
        scn = srow[id];
      }

      const float4 cb = cbv;
      const float sc = scv;
      const float ca = fmaxf(cb.z - cb.x, 0.f) * fmaxf(cb.w - cb.y, 0.f);
      bool su = ((c << 6) + lane) >= ncand;   // invalid lanes start dead

      // pre-test vs all accepts made before this chunk
      for (int j = 0; j < nacc; ++j) {
        float4 ab = accb[j];                  // uniform addr -> broadcast
        float aa = acca[j];
        float ix0 = fmaxf(ab.x, cb.x), iy0 = fmaxf(ab.y, cb.y);
        float ix1 = fminf(ab.z, cb.z), iy1 = fminf(ab.w, cb.w);
        float inter = fmaxf(ix1 - ix0, 0.f) * fmaxf(iy1 - iy0, 0.f);
        float den = fmaxf((aa + ca) - inter, 1e-8f);
        su = su || iou_gt(inter, den);
      }

      // serial resolve: accept lowest live lane, suppress vs it, repeat
      unsigned long long live = __ballot(!su);
      while (live && nacc < NMSMAX) {
        int l = __ffsll(live) - 1;
        float bx = rdlanef(cb.x, l), by = rdlanef(cb.y, l);
        float bz = rdlanef(cb.z, l), bw = rdlanef(cb.w, l);
        float bs = rdlanef(sc, l);
        float aa = fmaxf(bz - bx, 0.f) * fmaxf(bw - by, 0.f);
        if (lane == 0) {
          float* gr = grow + nacc * 6;
          gr[0] = fcls;
          gr[1] = bs;
          gr[2] = bx; gr[3] = by; gr[4] = bz; gr[5] = bw;
          accb[nacc] = make_float4(bx, by, bz, bw);
          acca[nacc] = aa;
        }
        ++nacc;
        // incremental suppression vs the new accept
        float ix0 = fmaxf(bx, cb.x), iy0 = fmaxf(by, cb.y);
        float ix1 = fminf(bz, cb.z), iy1 = fminf(bw, cb.w);
        float inter = fmaxf(ix1 - ix0, 0.f) * fmaxf(iy1 - iy0, 0.f);
        float den = fmaxf((aa + ca) - inter, 1e-8f);
        su = su || iou_gt(inter, den) || (lane == l);
        live = __ballot(!su);
      }

      cbv = cbn; scv = scn;
    }
  }

  // ---- zero-fill rows past the accepted count (ref: ok = 0 rows) -------
  for (int j = nacc * 6 + lane; j < NMSMAX * 6; j += 64) grow[j] = 0.f;
}

// ------------------------------------------------------- fused NMS fallback ---
// Round-3 kernel, used only when d_ws is too small for the split pipeline.
__global__ __launch_bounds__(NTHR) void nms_fused_kernel(
    const float* __restrict__ boxes,
    const float* __restrict__ scores_t,   // may be null -> strided fallback
    const float* __restrict__ pred,
    float* __restrict__ rows) {
#pragma clang fp contract(off)
  const int g = blockIdx.x;
  const int b = g / NCLS;
  const int c1 = g % NCLS;
  const int tid = threadIdx.x;
  const int lane = tid & 63;
  const int wid = tid >> 6;

  __shared__ unsigned long long keys[NANCH];
  __shared__ unsigned off[NBUCK];
  __shared__ unsigned wsum[8];
  __shared__ float4 accb[NMSMAX];
  __shared__ float acca[NMSMAX];
  __shared__ int nacc_s;

  const float* bimg = boxes + (long long)b * NANCH * 4;
  float* grow = rows + (long long)g * NMSMAX * 6;

  for (int q = 0; q < NBUCK / NTHR; ++q) off[tid + q * NTHR] = 0u;
  __syncthreads();

  unsigned sflip[NE];
  short bkt[NE];
#pragma unroll
  for (int k = 0; k < NE; ++k) {
    int i = tid + (k << 9);
    bkt[k] = -1;
    if (i < NANCH) {
      float s = scores_t
          ? scores_t[((long long)b * NCLS + c1) * NANCH + i]
          : pred[((long long)b * NANCH + i) * PRED_STRIDE + 1 + c1];
      if (s > 0.5f) {
        int bb = bucket_of(s);
        bkt[k] = (short)bb;
        sflip[k] = flipf(s);
        atomicAdd(&off[bb], 1u);
      }
    }
  }
  __syncthreads();

  {
    unsigned v0 = off[(tid << 2) + 0], v1 = off[(tid << 2) + 1];
    unsigned v2 = off[(tid << 2) + 2], v3 = off[(tid << 2) + 3];
    unsigned ls = v0 + v1 + v2 + v3;
    unsigned x = ls;
#pragma unroll
    for (int d = 1; d < 64; d <<= 1) {
      unsigned y = __shfl_up(x, d);
      if (lane >= d) x += y;
    }
    if (lane == 63) wsum[wid] = x;
    __syncthreads();
    unsigned wbase = 0;
    for (int w = 0; w < wid; ++w) wbase += wsum[w];
    unsigned base = wbase + x - ls;
    off[(tid << 2) + 0] = base;
    off[(tid << 2) + 1] = base + v0;
    off[(tid << 2) + 2] = base + v0 + v1;
    off[(tid << 2) + 3] = base + v0 + v1 + v2;
  }
  __syncthreads();

#pragma unroll
  for (int k = 0; k < NE; ++k) {
    if (bkt[k] >= 0) {
      int i = tid + (k << 9);
      unsigned long long key = ((unsigned long long)sflip[k] << 32) |
                               (unsigned)(0xFFFFFFFFu - (unsigned)i);
      unsigned slot = atomicAdd(&off[(int)bkt[k]], 1u);
      keys[slot] = key;
    }
  }
  __syncthreads();

  for (int q = 0; q < NBUCK / NTHR; ++q) {
    int bk = tid * (NBUCK / NTHR) + q;
    int st = bk ? (int)off[bk - 1] : 0;
    int en = (int)off[bk];
    for (int i = st + 1; i < en; ++i) {
      unsigned long long k = keys[i];
      int j = i - 1;
      while (j >= st && keys[j] < k) { keys[j + 1] = keys[j]; --j; }
      keys[j + 1] = k;
    }
  }
  __syncthreads();

  const int ncand = (int)off[NBUCK - 1];

  if (wid == 0 && ncand > 0) {
    const float fcls = (float)(c1 + 1);
    int nacc = 0;
    const int nchunk = (ncand + 63) >> 6;

    int slot0 = lane < ncand ? lane : 0;
    unsigned long long kcur = keys[slot0];
    float4 cbv;
    {
      unsigned bidx = 0xFFFFFFFFu - (unsigned)(kcur & 0xFFFFFFFFu);
      cbv = *(const float4*)(bimg + (long long)bidx * 4);
    }

    for (int c = 0; c < nchunk && nacc < NMSMAX; ++c) {
      unsigned long long knxt = 0ull;
      float4 cbn = make_float4(0.f, 0.f, 0.f, 0.f);
      if (c + 1 < nchunk) {
        int sl = ((c + 1) << 6) + lane;
        int cl = sl < ncand ? sl : 0;
        knxt = keys[cl];
        unsigned bidx = 0xFFFFFFFFu - (unsigned)(knxt & 0xFFFFFFFFu);
        cbn = *(const float4*)(bimg + (long long)bidx * 4);
      }

      const float4 cb = cbv;
      const float ca = fmaxf(cb.z - cb.x, 0.f) * fmaxf(cb.w - cb.y, 0.f);
      bool su = ((c << 6) + lane) >= ncand;

      for (int j = 0; j < nacc; ++j) {
        float4 ab = accb[j];
        float aa = acca[j];
        float ix0 = fmaxf(ab.x, cb.x), iy0 = fmaxf(ab.y, cb.y);
        float ix1 = fminf(ab.z, cb.z), iy1 = fminf(ab.w, cb.w);
        float inter = fmaxf(ix1 - ix0, 0.f) * fmaxf(iy1 - iy0, 0.f);
        float den = fmaxf((aa + ca) - inter, 1e-8f);
        su = su || iou_gt(inter, den);
      }

      unsigned long long live = __ballot(!su);
      while (live && nacc < NMSMAX) {
        int l = __ffsll(live) - 1;
        float bx = rdlanef(cb.x, l), by = rdlanef(cb.y, l);
        float bz = rdlanef(cb.z, l), bw = rdlanef(cb.w, l);
        unsigned khi = __builtin_amdgcn_readlane((unsigned)(kcur >> 32), l);
        float aa = fmaxf(bz - bx, 0.f) * fmaxf(bw - by, 0.f);
        if (lane == 0) {
          float* gr = grow + nacc * 6;
          gr[0] = fcls;
          gr[1] = unflipf(khi);
          gr[2] = bx; gr[3] = by; gr[4] = bz; gr[5] = bw;
          accb[nacc] = make_float4(bx, by, bz, bw);
          acca[nacc] = aa;
        }
        ++nacc;
        float ix0 = fmaxf(bx, cb.x), iy0 = fmaxf(by, cb.y);
        float ix1 = fminf(bz, cb.z), iy1 = fminf(bw, cb.w);
        float inter = fmaxf(ix1 - ix0, 0.f) * fmaxf(iy1 - iy0, 0.f);
        float den = fmaxf((aa + ca) - inter, 1e-8f);
        su = su || iou_gt(inter, den) || (lane == l);
        live = __ballot(!su);
      }

      kcur = knxt; cbv = cbn;
    }
    if (lane == 0) nacc_s = nacc;
  } else if (tid == 0 && ncand == 0) {
    nacc_s = 0;
  }
  __syncthreads();

  for (int j = nacc_s * 6 + tid; j < NMSMAX * 6; j += NTHR) grow[j] = 0.f;
}

// ----------------------------------------------------------------- top-k ---
__global__ __launch_bounds__(512) void topk_kernel(const float* __restrict__ rows,
                                                   float* __restrict__ out) {
  __shared__ unsigned long long key[2048];
  const int b = blockIdx.x;
  const int tid = threadIdx.x;  // 512 threads
  const float* rb = rows + (long long)b * (NCLS * NMSMAX) * 6;

  for (int e = tid; e < 2048; e += 512) {
    unsigned long long k = 0ull;  // padding sorts last (scores are >= 0)
    if (e < NCLS * NMSMAX) {
      float s = rb[e * 6 + 1];
      unsigned se = flipf(s);
      k = ((unsigned long long)se << 32) | (unsigned)(0xFFFFFFFFu - (unsigned)e);
    }
    key[e] = k;
  }
  __syncthreads();

  for (unsigned k2 = 2; k2 <= 2048; k2 <<= 1) {
    for (unsigned j = k2 >> 1; j > 0; j >>= 1) {
      for (unsigned t = tid; t < 1024; t += 512) {
        unsigned i = t + (t & ~(j - 1));
        unsigned l = i + j;
        bool up = ((i & k2) == 0);
        unsigned long long a = key[i], c = key[l];
        if (up ? (a < c) : (a > c)) { key[i] = c; key[l] = a; }
      }
      __syncthreads();
    }
  }

  if (tid < TOPK) {
    unsigned long long kk = key[tid];
    unsigned e = 0xFFFFFFFFu - (unsigned)(kk & 0xFFFFFFFFu);
    const float* src = rb + (long long)e * 6;
    float* dst = out + ((long long)b * TOPK + tid) * 6;
#pragma unroll
    for (int j = 0; j < 6; ++j) dst[j] = src[j];
  }
}

// ---------------------------------------------------------------- launch ---
extern "C" void kernel_launch(void* const* d_in, const int* in_sizes, int n_in,
                              void* d_out, int out_size, void* d_ws, size_t ws_size,
                              hipStream_t stream) {
  const float* pred = (const float*)d_in[0];
  float* out = (float*)d_out;
  float* ws = (float*)d_ws;

  const long long boxes_f = (long long)NB * NANCH * 4;           //  2,235,392
  const long long rows_f  = (long long)NB * NCLS * NMSMAX * 6;   //    768,000
  const long long st_f    = (long long)NB * NCLS * NANCH;        // 11,176,960
  const long long sidx_f  = (long long)NB * NCLS * NANCH / 2;    //  5,588,480
  const long long ncand_f = NB * NCLS;                           //      1,280

  float* boxes = ws;
  float* rows  = ws + boxes_f;
  float* st    = ws + boxes_f + rows_f;
  unsigned short* sidx = (unsigned short*)(ws + boxes_f + rows_f + st_f);
  int* ncand = (int*)(ws + boxes_f + rows_f + st_f + sidx_f);

  size_t need_scores = (size_t)(boxes_f + rows_f + st_f) * sizeof(float);
  size_t need_full   = (size_t)(boxes_f + rows_f + st_f + sidx_f + ncand_f) * sizeof(float);

  bool have_scores = ws_size >= need_scores;
  bool full = ws_size >= need_full;
  float* scores_t = have_scores ? st : nullptr;

  dim3 dgrid((NANCH + DTILE - 1) / DTILE, NB);
  decode_kernel<<<dgrid, 256, 0, stream>>>(pred, boxes, scores_t);

  if (full) {
    sort_kernel<<<NB * NCLS, NTHR, 0, stream>>>(scores_t, sidx, ncand);
    scan_kernel<<<NB * NCLS, 64, 0, stream>>>(boxes, scores_t, sidx, ncand, rows);
  } else {
    nms_fused_kernel<<<NB * NCLS, NTHR, 0, stream>>>(boxes, scores_t, pred, rows);
  }
  topk_kernel<<<NB, 512, 0, stream>>>(rows, out);
}